// Round 1
// 507.688 us; speedup vs baseline: 1.0592x; 1.0592x over previous
//
#include <hip/hip_runtime.h>
#include <cstdint>
#include <cstddef>

#define IN_F   4096
#define OUT_F  4096
#define NTOK   8192
#define NGRP   32

// ---- GEMM geometry: 256^2 8-phase template (T1+T2+T3+T4+T5) ----
#define BM 256
#define BN 256
#define BK 64
#define KTILES   (IN_F / BK)     // 64
#define LDS_TILE (BM * BK)       // 16384 elements (32 KiB) per buffer per operand

typedef __attribute__((ext_vector_type(8))) __bf16 bf16x8;
typedef __attribute__((ext_vector_type(4))) float  floatx4;

// fp32 -> bf16 bits, round-to-nearest-even
__device__ __forceinline__ unsigned short f2bf(float f) {
    unsigned int u = __builtin_bit_cast(unsigned int, f);
    u += 0x7fffu + ((u >> 16) & 1u);
    return (unsigned short)(u >> 16);
}

// async global -> LDS, 16B per lane. LDS dest is wave-uniform base + lane*16.
__device__ __forceinline__ void gload16(const void* g, void* l) {
    __builtin_amdgcn_global_load_lds(
        (const __attribute__((address_space(1))) void*)g,
        (__attribute__((address_space(3))) void*)l,
        16, 0, 0);
}

// ---------------------------------------------------------------------------
// 1) Dequant: qweight [K/8][N] int32 (8 nibbles along K) -> Wt [N][K] bf16.
//    (unchanged from previous verified version)
// ---------------------------------------------------------------------------
__global__ void dequant_kernel(const int* __restrict__ qweight,
                               const int* __restrict__ qzeros,
                               const float* __restrict__ scales,
                               const int* __restrict__ g_idx,
                               unsigned short* __restrict__ Wt) {
    __shared__ unsigned short tile[256 * 64];   // 32 KB
    const int tk  = blockIdx.x & 63;    // 64 k-tiles (8 k8-rows each)
    const int tn  = blockIdx.x >> 6;    // 16 n-tiles
    const int tid = threadIdx.x;
    const int n   = tn * 256 + tid;

#pragma unroll
    for (int r = 0; r < 8; ++r) {
        const int k8 = tk * 8 + r;
        const int k  = k8 * 8;
        const int g  = g_idx[k];                          // uniform -> scalar load
        const int qw = qweight[(size_t)k8 * OUT_F + n];   // lanes sweep n: coalesced
        const float s = scales[g * OUT_F + n];
        const int  zw = qzeros[g * (OUT_F / 8) + (n >> 3)];
        const float z = (float)(((zw >> (4 * (n & 7))) & 15) + 1);
        const float sz = s * z;
        union { unsigned short h[8]; uint4 v; } u;
#pragma unroll
        for (int j = 0; j < 8; ++j)
            u.h[j] = f2bf(s * (float)((qw >> (4 * j)) & 15) - sz);
        // chunk r stored at swizzled position r ^ (tid&7): conflict-free write
        *(uint4*)(tile + tid * 64 + ((r ^ (tid & 7)) * 8)) = u.v;
    }
    __syncthreads();
#pragma unroll
    for (int i = 0; i < 8; ++i) {
        const int nl = i * 32 + (tid >> 3);
        const int c  = tid & 7;
        const uint4 v = *(const uint4*)(tile + nl * 64 + ((c ^ (nl & 7)) * 8));
        *(uint4*)(Wt + (size_t)(tn * 256 + nl) * IN_F + tk * 64 + c * 8) = v;
    }
}

// ---------------------------------------------------------------------------
// 2) x fp32 -> bf16, 8 elements/thread (unchanged)
// ---------------------------------------------------------------------------
__global__ void xcast_kernel(const float* __restrict__ x,
                             unsigned short* __restrict__ Xb) {
    const size_t i = ((size_t)blockIdx.x * 256 + threadIdx.x) * 8;
    const float4 a = *(const float4*)(x + i);
    const float4 b = *(const float4*)(x + i + 4);
    union { unsigned short h[8]; uint4 v; } u;
    u.h[0] = f2bf(a.x); u.h[1] = f2bf(a.y); u.h[2] = f2bf(a.z); u.h[3] = f2bf(a.w);
    u.h[4] = f2bf(b.x); u.h[5] = f2bf(b.y); u.h[6] = f2bf(b.z); u.h[7] = f2bf(b.w);
    *(uint4*)(Xb + i) = u.v;
}

// ---------------------------------------------------------------------------
// 3) GEMM: out[M][N] = Xb[M][K] * Wt[N][K]^T + bias
//    256x256 tile, BK=64, 512 threads = 8 waves (2M x 4N), double-buffered
//    128 KiB LDS, 4 phases per K-tile:
//      phase = { ds_read frag subset | stage 1 half-class via global_load_lds
//                | counted vmcnt | s_barrier | setprio(1) 16xMFMA setprio(0)
//                | s_barrier }
//    vmcnt never drains to 0 in the main loop (T4). Chunk swizzle
//    pos = chunk ^ (row&7) applied on pre-permuted global source (write side,
//    since global_load_lds writes linearly) and on ds_read address (read side).
//    Staging classes grouped by need-phase:
//      SA1 = A rows {0..63}u{128..191}   (read in phase 1 by both wave rows)
//      SA3 = A rows {64..127}u{192..255} (read in phase 3)
//      SB1 = B rows with bit5==0        (j=0,1 frags, phase 1)
//      SB2 = B rows with bit5==1        (j=2,3 frags, phase 2)
//    FIFO invariant entering each tile: outstanding = [SB2(t), SA3(t)] (4 loads).
// ---------------------------------------------------------------------------
#define VMCNT4() asm volatile("s_waitcnt vmcnt(4)" ::: "memory")
#define VMCNT2() asm volatile("s_waitcnt vmcnt(2)" ::: "memory")
#define VMCNT0() asm volatile("s_waitcnt vmcnt(0)" ::: "memory")
#define BARRIER() do { __builtin_amdgcn_s_barrier(); asm volatile("" ::: "memory"); } while (0)

template<int I0, int J0>
__device__ __forceinline__ void quad(floatx4 (&acc)[8][4],
                                     const bf16x8 (&av)[4][2],
                                     const bf16x8 (&bv)[4][2]) {
#pragma unroll
    for (int i4 = 0; i4 < 4; ++i4)
#pragma unroll
        for (int jj = 0; jj < 2; ++jj)
#pragma unroll
            for (int kk = 0; kk < 2; ++kk)
                acc[I0 + i4][J0 + jj] = __builtin_amdgcn_mfma_f32_16x16x32_bf16(
                    av[i4][kk], bv[J0 + jj][kk], acc[I0 + i4][J0 + jj], 0, 0, 0);
}

__global__ __launch_bounds__(512, 2) void gemm_kernel(
        const unsigned short* __restrict__ Xb,
        const unsigned short* __restrict__ Wt,
        const float* __restrict__ bias,
        float* __restrict__ out) {
    __shared__ unsigned short As[2 * LDS_TILE];   // 64 KiB
    __shared__ unsigned short Bs[2 * LDS_TILE];   // 64 KiB

    const int tid  = threadIdx.x;
    const int wave = tid >> 6;
    const int lane = tid & 63;
    const int mi   = lane & 15;
    const int kq   = lane >> 4;

    // T1: XCD-aware bijective swizzle (512 blocks, 8 XCDs, 512%8==0).
    // Within an XCD's 64-block chunk, tn varies fastest -> the 2 live A-panels
    // (2 MiB each) stay L2-resident while B panels stream (L3 holds all of Wt).
    const int bid = blockIdx.x;
    const int swz = (bid & 7) * 64 + (bid >> 3);
    const int m0  = (swz >> 4) * BM;    // 32 m-tiles
    const int n0  = (swz & 15) * BN;    // 16 n-tiles

    const int wrow = (wave >> 2) * 128;     // 0 / 128
    const int wcol = (wave & 3) * 64;       // 0 / 64 / 128 / 192

    // staging: per gload16, lane l covers row (l>>3), chunk-pos (l&7) of an
    // 8-row x 128B block; global chunk = pos ^ (row&7)  (involution, r0%8==0)
    const int lrow   = lane >> 3;
    const int lchunk = ((lane & 7) ^ lrow) * 8;
    const unsigned short* aSrc = Xb + (size_t)(m0 + lrow) * IN_F + lchunk;
    const unsigned short* bSrc = Wt + (size_t)(n0 + lrow) * IN_F + lchunk;

    const int raA = (wave >> 2) * 128 + (wave & 3) * 16;  // + h*64 -> SA class rows
    const int raB = (wave >> 1) * 64  + (wave & 1) * 16;  // + h*32 -> SB class rows

    // fragment read bases; chunk-pos = (kk*4+kq) ^ (mi&7)
    const int aRd = (wrow + mi) * BK;
    const int bRd = (wcol + mi) * BK;
    const int cp0 = ((kq)     ^ (mi & 7)) * 8;
    const int cp1 = ((4 + kq) ^ (mi & 7)) * 8;

    floatx4 acc[8][4];
#pragma unroll
    for (int i = 0; i < 8; ++i)
#pragma unroll
        for (int j = 0; j < 4; ++j)
            acc[i][j] = floatx4{0.f, 0.f, 0.f, 0.f};

    bf16x8 av[4][2], bv[4][2];

    auto stageA = [&](int bufofs, int h, int kt) {
        const int r0 = raA + h * 64;
        gload16(aSrc + (size_t)(r0 + 0) * IN_F + (size_t)kt * BK,
                (void*)(As + bufofs + (r0 + 0) * BK));
        gload16(aSrc + (size_t)(r0 + 8) * IN_F + (size_t)kt * BK,
                (void*)(As + bufofs + (r0 + 8) * BK));
    };
    auto stageB = [&](int bufofs, int h, int kt) {
        const int r0 = raB + h * 32;
        gload16(bSrc + (size_t)(r0 + 0) * IN_F + (size_t)kt * BK,
                (void*)(Bs + bufofs + (r0 + 0) * BK));
        gload16(bSrc + (size_t)(r0 + 8) * IN_F + (size_t)kt * BK,
                (void*)(Bs + bufofs + (r0 + 8) * BK));
    };
    auto ldah = [&](int bufofs, int ah) {           // A rows wrow + (ah*4+i4)*16 + mi
#pragma unroll
        for (int i4 = 0; i4 < 4; ++i4) {
            av[i4][0] = *(const bf16x8*)(As + bufofs + aRd + (ah * 4 + i4) * (16 * BK) + cp0);
            av[i4][1] = *(const bf16x8*)(As + bufofs + aRd + (ah * 4 + i4) * (16 * BK) + cp1);
        }
    };
    auto ldb01 = [&](int bufofs) {                  // B frags j=0,1
#pragma unroll
        for (int jj = 0; jj < 2; ++jj) {
            bv[jj][0] = *(const bf16x8*)(Bs + bufofs + bRd + jj * (16 * BK) + cp0);
            bv[jj][1] = *(const bf16x8*)(Bs + bufofs + bRd + jj * (16 * BK) + cp1);
        }
    };
    auto ldb23 = [&](int bufofs) {                  // B frags j=2,3
#pragma unroll
        for (int jj = 0; jj < 2; ++jj) {
            bv[2 + jj][0] = *(const bf16x8*)(Bs + bufofs + bRd + (2 + jj) * (16 * BK) + cp0);
            bv[2 + jj][1] = *(const bf16x8*)(Bs + bufofs + bRd + (2 + jj) * (16 * BK) + cp1);
        }
    };

    // prologue: stage tile 0 in need order SA1, SB1, SB2, SA3; land first two.
    stageA(0, 0, 0);
    stageB(0, 0, 0);
    stageB(0, 1, 0);
    stageA(0, 1, 0);
    VMCNT4();
    BARRIER();

    for (int kt = 0; kt < KTILES - 1; ++kt) {
        const int bo = (kt & 1) * LDS_TILE;   // compute buffer
        const int no = bo ^ LDS_TILE;         // staging buffer (tile kt+1)
        const int kn = kt + 1;

        // ---- phase 1: quad (i 0..3, j 0..1) ----
        ldah(bo, 0); ldb01(bo);
        stageA(no, 0, kn);                    // SA1(kt+1)
        VMCNT4();                             // drains SB2(kt) for phase 2
        BARRIER();
        __builtin_amdgcn_s_setprio(1);
        quad<0, 0>(acc, av, bv);
        __builtin_amdgcn_s_setprio(0);
        BARRIER();

        // ---- phase 2: quad (i 0..3, j 2..3) ----
        ldb23(bo);
        stageB(no, 0, kn);                    // SB1(kt+1)
        VMCNT4();                             // drains SA3(kt) for phase 3
        BARRIER();
        __builtin_amdgcn_s_setprio(1);
        quad<0, 2>(acc, av, bv);
        __builtin_amdgcn_s_setprio(0);
        BARRIER();

        // ---- phase 3: quad (i 4..7, j 2..3) ----
        ldah(bo, 1);
        stageB(no, 1, kn);                    // SB2(kt+1)
        BARRIER();                            // no wait: phase 4 reads nothing
        __builtin_amdgcn_s_setprio(1);
        quad<4, 2>(acc, av, bv);
        __builtin_amdgcn_s_setprio(0);
        BARRIER();

        // ---- phase 4: quad (i 4..7, j 0..1) ----
        stageA(no, 1, kn);                    // SA3(kt+1)
        VMCNT4();                             // drains SA1(kt+1), SB1(kt+1)
        BARRIER();
        __builtin_amdgcn_s_setprio(1);
        quad<4, 0>(acc, av, bv);
        __builtin_amdgcn_s_setprio(0);
        BARRIER();
    }

    // ---- epilogue tile (kt = KTILES-1, buf = 1), no staging ----
    {
        const int bo = ((KTILES - 1) & 1) * LDS_TILE;
        ldah(bo, 0); ldb01(bo);
        VMCNT2();                             // drains SB2(last)
        BARRIER();
        __builtin_amdgcn_s_setprio(1);
        quad<0, 0>(acc, av, bv);
        __builtin_amdgcn_s_setprio(0);
        BARRIER();

        ldb23(bo);
        VMCNT0();                             // drains SA3(last)
        BARRIER();
        __builtin_amdgcn_s_setprio(1);
        quad<0, 2>(acc, av, bv);
        __builtin_amdgcn_s_setprio(0);
        BARRIER();

        ldah(bo, 1);
        __builtin_amdgcn_s_setprio(1);
        quad<4, 2>(acc, av, bv);
        quad<4, 0>(acc, av, bv);
        __builtin_amdgcn_s_setprio(0);
    }

    // C write: D layout col = lane&15, row = (lane>>4)*4 + reg  [m89/m91]
    const int mq = kq;
#pragma unroll
    for (int j = 0; j < 4; ++j) {
        const int col = n0 + wcol + j * 16 + mi;
        const float bb = bias[col];
#pragma unroll
        for (int i = 0; i < 8; ++i) {
#pragma unroll
            for (int r = 0; r < 4; ++r) {
                const int row = m0 + wrow + i * 16 + mq * 4 + r;
                out[(size_t)row * OUT_F + col] = acc[i][j][r] + bb;
            }
        }
    }
}

// ---------------------------------------------------------------------------
extern "C" void kernel_launch(void* const* d_in, const int* in_sizes, int n_in,
                              void* d_out, int out_size, void* d_ws, size_t ws_size,
                              hipStream_t stream) {
    const float* x       = (const float*)d_in[0];
    const int*   qweight = (const int*)d_in[1];
    const int*   qzeros  = (const int*)d_in[2];
    const float* scales  = (const float*)d_in[3];
    const int*   g_idx   = (const int*)d_in[4];
    const float* bias    = (const float*)d_in[5];
    float*       out     = (float*)d_out;

    unsigned short* Wt = (unsigned short*)d_ws;                 // 32 MiB
    unsigned short* Xb = Wt + (size_t)OUT_F * IN_F;             // 64 MiB

    dequant_kernel<<<64 * 16, 256, 0, stream>>>(qweight, qzeros, scales, g_idx, Wt);
    xcast_kernel<<<((size_t)NTOK * IN_F / 8) / 256, 256, 0, stream>>>(x, Xb);

    gemm_kernel<<<dim3((NTOK / BM) * (OUT_F / BN)), 512, 0, stream>>>(Xb, Wt, bias, out);
}